// Round 6
// baseline (988.258 us; speedup 1.0000x reference)
//
#include <hip/hip_runtime.h>

typedef unsigned short u16;
typedef __attribute__((ext_vector_type(8))) short short8;
typedef __attribute__((ext_vector_type(4))) float f32x4;

__device__ __forceinline__ u16 f32_to_bf16(float f) {
  unsigned u = __float_as_uint(f);
  u += 0x7fffu + ((u >> 16) & 1u);
  return (u16)(u >> 16);
}
__device__ __forceinline__ float bf16_to_f32(u16 h) {
  return __uint_as_float(((unsigned)h) << 16);
}

// async global->LDS, 16B per lane; lds dest = wave-uniform base + lane*16
#define GLD_LDS16(gp, lp)                                                  \
  __builtin_amdgcn_global_load_lds(                                        \
      (const __attribute__((address_space(1))) void*)(gp),                 \
      (__attribute__((address_space(3))) void*)(lp), 16, 0, 0)

// ---------------- fused 4-weight f32 -> bf16 conversion ----------------
__global__ __launch_bounds__(256) void cvt4_f32_bf16(const float* __restrict__ s0,
                                                     const float* __restrict__ s1,
                                                     const float* __restrict__ s2,
                                                     const float* __restrict__ s3,
                                                     u16* __restrict__ d0,
                                                     u16* __restrict__ d1,
                                                     u16* __restrict__ d2,
                                                     u16* __restrict__ d3) {
  const float* s = blockIdx.y == 0 ? s0 : blockIdx.y == 1 ? s1 : blockIdx.y == 2 ? s2 : s3;
  u16* d = blockIdx.y == 0 ? d0 : blockIdx.y == 1 ? d1 : blockIdx.y == 2 ? d2 : d3;
  int i = blockIdx.x * 256 + threadIdx.x;  // 65536 float4 per tensor
  float4 v = ((const float4*)s)[i];
  uint2 r;
  r.x = (unsigned)f32_to_bf16(v.x) | ((unsigned)f32_to_bf16(v.y) << 16);
  r.y = (unsigned)f32_to_bf16(v.z) | ((unsigned)f32_to_bf16(v.w) << 16);
  ((uint2*)d)[i] = r;
}

// ---------------- GroupNorm stats: mean/rstd per (b,g) ----------------
__global__ __launch_bounds__(1024) void gn_stats(const float* __restrict__ x,
                                                 float2* __restrict__ stats) {
  int bg = blockIdx.x;
  const float* xp = x + (long)bg * 65536;
  int t = threadIdx.x;
  float s = 0.f, ss = 0.f;
  for (int i = t; i < 16384; i += 1024) {
    float4 v = ((const float4*)xp)[i];
    s += (v.x + v.y) + (v.z + v.w);
    ss += (v.x * v.x + v.y * v.y) + (v.z * v.z + v.w * v.w);
  }
#pragma unroll
  for (int o = 32; o; o >>= 1) { s += __shfl_xor(s, o); ss += __shfl_xor(ss, o); }
  __shared__ float rs[16], rq[16];
  int wave = t >> 6, lane = t & 63;
  if (lane == 0) { rs[wave] = s; rq[wave] = ss; }
  __syncthreads();
  if (wave == 0) {
    float a = lane < 16 ? rs[lane] : 0.f;
    float b = lane < 16 ? rq[lane] : 0.f;
#pragma unroll
    for (int o = 8; o; o >>= 1) { a += __shfl_xor(a, o); b += __shfl_xor(b, o); }
    if (lane == 0) {
      float mean = a * (1.f / 65536.f);
      float var = b * (1.f / 65536.f) - mean * mean;
      stats[bg] = make_float2(mean, rsqrtf(var + 1e-6f));
    }
  }
}

// ---------------- GroupNorm apply + transpose -> hT[B][4096][512] ----------------
__global__ __launch_bounds__(256) void gn_apply_t(const float* __restrict__ x,
                                                  const float* __restrict__ gw,
                                                  const float* __restrict__ gb,
                                                  const float2* __restrict__ stats,
                                                  u16* __restrict__ hT) {
  const int g = blockIdx.y, bb = blockIdx.z;
  const float2 st = stats[bb * 32 + g];
  const float mean = st.x, rstd = st.y;
  const float* xp = x + ((long)bb * 512 + g * 16) * 4096;
  u16* hp = hT + (long)bb * 4096 * 512 + g * 16;
  const int i = blockIdx.x * 1024 + threadIdx.x * 4;
#pragma unroll
  for (int half = 0; half < 2; ++half) {
    float w[8], bv[8];
#pragma unroll
    for (int c = 0; c < 8; ++c) {
      w[c] = gw[g * 16 + half * 8 + c] * rstd;
      bv[c] = gb[g * 16 + half * 8 + c];
    }
    float v[8][4];
#pragma unroll
    for (int c = 0; c < 8; ++c) {
      float4 f = *(const float4*)(xp + (long)(half * 8 + c) * 4096 + i);
      v[c][0] = f.x; v[c][1] = f.y; v[c][2] = f.z; v[c][3] = f.w;
    }
#pragma unroll
    for (int p = 0; p < 4; ++p) {
      u16 o[8];
#pragma unroll
      for (int c = 0; c < 8; ++c) o[c] = f32_to_bf16((v[c][p] - mean) * w[c] + bv[c]);
      *(int4*)(hp + (long)(i + p) * 512 + half * 8) = *(int4*)o;
    }
  }
}

// ---------------- m97-style 128x128 bf16 MFMA GEMM (B^T form) ----------------
// C[m][n] = sum_k A[m][k] * B[n][k], K % 32 == 0, tiles 128x128.
// SWZ: 1D grid, XCD-aware remap assuming 4 x-tiles, 32 y-tiles (x-siblings on
// one XCD so a shared A-strip is fetched once per XCD L2, not 4x).
// EPI 0: bf16 out, LDS-transposed coalesced dwordx4 stores; EPI 1: f32 + residual.
template <int EPI, bool SWZ>
__global__ __launch_bounds__(256) void gemm128(
    const u16* __restrict__ Ab, long sA, int lda,
    const u16* __restrict__ Bb, long sB, int ldb,
    void* __restrict__ Cb, long sC, int ldc,
    const float* __restrict__ biasM, const float* __restrict__ biasN,
    float scale, const float* __restrict__ res, long sR, int K) {
  int bx, by, bz;
  if (SWZ) {
    const int lid = blockIdx.x;
    const int xcd = lid & 7, s = lid >> 3;
    bx = s & 3;                      // x fastest within an XCD -> A-strip reuse
    const int rest = s >> 2;
    by = xcd + 8 * (rest & 3);       // 4 y-strips per XCD before moving on
    bz = rest >> 2;
  } else {
    bx = blockIdx.x; by = blockIdx.y; bz = blockIdx.z;
  }
  const u16* A = Ab + (long)bz * sA;
  const u16* B = Bb + (long)bz * sB;
  const int m0 = by * 128, n0 = bx * 128;
  const int t = threadIdx.x;
  const int wave = t >> 6, lane = t & 63;
  const int wy = wave >> 1, wx = wave & 1;
  const int lr = lane & 15, q = lane >> 4;
  // LDS pool: K-loop uses As(8K)+Bs(8K); epilogue reuses it as Cs 128x136 u16 (34K)
  __shared__ __align__(16) char smem[34816];
  u16* As = (u16*)smem;        // [128][32] row-major, no pad (DMA layout)
  u16* Bs = As + 128 * 32;     // [128][32]
  f32x4 acc[4][4] = {};
  // staging: tile = 8192 B = 512 chunks of 16 B; chunk = c*256 + t
  for (int k0 = 0; k0 < K; k0 += 32) {
#pragma unroll
    for (int c = 0; c < 2; ++c) {
      const int chunk = c * 256 + t;
      const int row = chunk >> 2, ko = (chunk & 3) << 3;
      const int ldsoff = (c * 256 + wave * 64) * 8;  // u16 units, wave-uniform
      GLD_LDS16(A + (long)(m0 + row) * lda + (k0 + ko), As + ldsoff);
      GLD_LDS16(B + (long)(n0 + row) * ldb + (k0 + ko), Bs + ldsoff);
    }
    __syncthreads();
    short8 af[4], bf[4];
#pragma unroll
    for (int i = 0; i < 4; ++i)
      af[i] = *(const short8*)(&As[(wy * 64 + i * 16 + lr) * 32 + q * 8]);
#pragma unroll
    for (int j = 0; j < 4; ++j)
      bf[j] = *(const short8*)(&Bs[(wx * 64 + j * 16 + lr) * 32 + q * 8]);
#pragma unroll
    for (int i = 0; i < 4; ++i)
#pragma unroll
      for (int j = 0; j < 4; ++j)
        acc[i][j] = __builtin_amdgcn_mfma_f32_16x16x32_bf16(af[i], bf[j], acc[i][j], 0, 0, 0);
    __syncthreads();
  }
  // epilogue: frag D col=lane&15, row=(lane>>4)*4+r
  if (EPI == 0) {
    u16* Cs = (u16*)smem;  // 128 x 136 (pad 8: quad-stride conflicts 2-way=free)
#pragma unroll
    for (int i = 0; i < 4; ++i) {
#pragma unroll
      for (int r = 0; r < 4; ++r) {
        const int ml = wy * 64 + i * 16 + q * 4 + r;
        const float bm = biasM ? biasM[m0 + ml] : 0.f;
#pragma unroll
        for (int j = 0; j < 4; ++j) {
          const int nl = wx * 64 + j * 16 + lr;
          float vv = acc[i][j][r] + bm;
          if (biasN) vv += biasN[n0 + nl];
          Cs[ml * 136 + nl] = f32_to_bf16(vv * scale);
        }
      }
    }
    __syncthreads();
    const int row = t >> 1, cb = (t & 1) * 64;
    u16* gout = (u16*)Cb + (long)bz * sC + (long)(m0 + row) * ldc + n0 + cb;
    const u16* ls = Cs + row * 136 + cb;
#pragma unroll
    for (int u = 0; u < 8; ++u) ((int4*)gout)[u] = *(const int4*)(ls + u * 8);
  } else {
#pragma unroll
    for (int i = 0; i < 4; ++i) {
#pragma unroll
      for (int r = 0; r < 4; ++r) {
        const int mr = m0 + wy * 64 + i * 16 + q * 4 + r;
        const float bm = biasM ? biasM[mr] : 0.f;
#pragma unroll
        for (int j = 0; j < 4; ++j) {
          const int nc = n0 + wx * 64 + j * 16 + lr;
          float vv = (acc[i][j][r] + bm) * scale;
          const long off = (long)bz * sC + (long)mr * ldc + nc;
          ((float*)Cb)[off] = vv + res[(long)bz * sR + (long)mr * ldc + nc];
        }
      }
    }
  }
}

// ---------------- row softmax, in place on bf16 [4096 x 4096] per batch ----------------
__global__ __launch_bounds__(256) void softmax_kernel(u16* __restrict__ P) {
  u16* pr = P + (long)blockIdx.y * 4096 * 4096 + (long)blockIdx.x * 4096;
  int t = threadIdx.x;
  int lane = t & 63, wave = t >> 6;
  int4 d0 = ((const int4*)pr)[t];
  int4 d1 = ((const int4*)pr)[t + 256];
  const u16* p0 = (const u16*)&d0;
  const u16* p1 = (const u16*)&d1;
  float v[16];
#pragma unroll
  for (int j = 0; j < 8; ++j) { v[j] = bf16_to_f32(p0[j]); v[8 + j] = bf16_to_f32(p1[j]); }
  float mx = v[0];
#pragma unroll
  for (int j = 1; j < 16; ++j) mx = fmaxf(mx, v[j]);
#pragma unroll
  for (int o = 32; o; o >>= 1) mx = fmaxf(mx, __shfl_xor(mx, o));
  __shared__ float sm[4];
  __shared__ float ssum[4];
  if (lane == 0) sm[wave] = mx;
  __syncthreads();
  mx = fmaxf(fmaxf(sm[0], sm[1]), fmaxf(sm[2], sm[3]));
  float s = 0.f;
#pragma unroll
  for (int j = 0; j < 16; ++j) { v[j] = __expf(v[j] - mx); s += v[j]; }
#pragma unroll
  for (int o = 32; o; o >>= 1) s += __shfl_xor(s, o);
  if (lane == 0) ssum[wave] = s;
  __syncthreads();
  s = ssum[0] + ssum[1] + ssum[2] + ssum[3];
  float inv = 1.0f / s;
  unsigned r0[4], r1[4];
#pragma unroll
  for (int j = 0; j < 4; ++j) {
    r0[j] = (unsigned)f32_to_bf16(v[2 * j] * inv) | ((unsigned)f32_to_bf16(v[2 * j + 1] * inv) << 16);
    r1[j] = (unsigned)f32_to_bf16(v[8 + 2 * j] * inv) | ((unsigned)f32_to_bf16(v[8 + 2 * j + 1] * inv) << 16);
  }
  ((int4*)pr)[t] = *(int4*)r0;
  ((int4*)pr)[t + 256] = *(int4*)r1;
}

extern "C" void kernel_launch(void* const* d_in, const int* in_sizes, int n_in,
                              void* d_out, int out_size, void* d_ws, size_t ws_size,
                              hipStream_t stream) {
  const float* x = (const float*)d_in[0];
  const float* gn_w = (const float*)d_in[1];
  const float* gn_b = (const float*)d_in[2];
  const float* q_w = (const float*)d_in[3];
  const float* q_b = (const float*)d_in[4];
  const float* k_w = (const float*)d_in[5];
  const float* k_b = (const float*)d_in[6];
  const float* v_w = (const float*)d_in[7];
  const float* v_b = (const float*)d_in[8];
  const float* p_w = (const float*)d_in[9];
  const float* p_b = (const float*)d_in[10];

  char* ws = (char*)d_ws;
  const size_t MB = 1ull << 20;
  u16* wqb = (u16*)(ws + 0);              // 512 KB each
  u16* wkb = (u16*)(ws + 512 * 1024);
  u16* wvb = (u16*)(ws + 1 * MB);
  u16* wpb = (u16*)(ws + 3 * MB / 2);
  u16* hb = (u16*)(ws + 2 * MB);          // 32 MB: hT, later reused as oT
  u16* vb = (u16*)(ws + 34 * MB);         // 32 MB: v [C][N]
  u16* Pb = (u16*)(ws + 66 * MB);         // 32*NB MB: score groups
  float2* stats = (float2*)(ws + 66 * MB);  // 4 KB, temporally disjoint from Pb
  u16* qb = (u16*)d_out;                  // 32 MB scratch (dead before proj)
  u16* kb = (u16*)d_out + 512L * 4096 * 8;
  u16* ob = hb;

  int NB = 1;
  if (ws_size >= 66 * MB + 8 * 32 * MB) NB = 8;
  else if (ws_size >= 66 * MB + 4 * 32 * MB) NB = 4;
  else if (ws_size >= 66 * MB + 2 * 32 * MB) NB = 2;

  cvt4_f32_bf16<<<dim3(256, 4), 256, 0, stream>>>(q_w, k_w, v_w, p_w, wqb, wkb, wvb, wpb);
  gn_stats<<<256, 1024, 0, stream>>>(x, stats);
  gn_apply_t<<<dim3(4, 32, 8), 256, 0, stream>>>(x, gn_w, gn_b, stats, hb);

  const long sCN = 512L * 4096;
  const long sNN = 4096L * 4096;
  const float scale = 0.04419417382415922f;  // 512^-0.5, folded into q

  // qT[i][c'] = sum_c hT[i][c] qw[c'][c]; M=4096 N=512 K=512
  gemm128<0, false><<<dim3(4, 32, 8), 256, 0, stream>>>(
      hb, sCN, 512, wqb, 0, 512, qb, sCN, 512, nullptr, q_b, scale, nullptr, 0, 512);
  gemm128<0, false><<<dim3(4, 32, 8), 256, 0, stream>>>(
      hb, sCN, 512, wkb, 0, 512, kb, sCN, 512, nullptr, k_b, 1.0f, nullptr, 0, 512);
  // v[c'][j] = sum_c vw[c'][c] hT[j][c]; M=512 N=4096 K=512
  gemm128<0, false><<<dim3(32, 4, 8), 256, 0, stream>>>(
      wvb, 0, 512, hb, sCN, 512, vb, sCN, 4096, v_b, nullptr, 1.0f, nullptr, 0, 512);

  for (int b0 = 0; b0 < 8; b0 += NB) {
    // S[i][j] = sum_c qT[i][c] kT[j][c]; M=N=4096 K=512
    gemm128<0, false><<<dim3(32, 32, NB), 256, 0, stream>>>(
        qb + b0 * sCN, sCN, 512, kb + b0 * sCN, sCN, 512, Pb, sNN, 4096,
        nullptr, nullptr, 1.0f, nullptr, 0, 512);
    softmax_kernel<<<dim3(4096, NB), 256, 0, stream>>>(Pb);
    // oT[i][c'] = sum_j P[i][j] v[c'][j]; M=4096 N=512 K=4096 — XCD-swizzled
    gemm128<0, true><<<128 * NB, 256, 0, stream>>>(
        Pb, sNN, 4096, vb + b0 * sCN, sCN, 4096, ob + b0 * sCN, sCN, 512,
        nullptr, nullptr, 1.0f, nullptr, 0, 4096);
  }

  // out[c'][i] = sum_d pw[c'][d] oT[i][d] + pb[c'] + x; M=512 N=4096 K=512, f32
  gemm128<1, false><<<dim3(32, 4, 8), 256, 0, stream>>>(
      wpb, 0, 512, ob, sCN, 512, (float*)d_out, sCN, 4096, p_b, nullptr, 1.0f,
      x, sCN, 512);
}